// Round 1
// baseline (608.076 us; speedup 1.0000x reference)
//
#include <hip/hip_runtime.h>

#define N_PTS 262144
#define C_DIM 256
#define S_SEG 16

typedef __attribute__((ext_vector_type(8))) short bf16x8;
typedef __attribute__((ext_vector_type(4))) float f32x4;

__device__ __forceinline__ short f2bf(float f) {
    unsigned u = __builtin_bit_cast(unsigned, f);
    u += 0x7FFF + ((u >> 16) & 1);   // round-to-nearest-even
    return (short)(u >> 16);
}

// ---------------- Kernel 0: normalize offsets (int64 or int32 in memory) -> int32 ----
__global__ void k0_norm_o(const int* __restrict__ o_raw, int* __restrict__ o32) {
    int t = threadIdx.x;
    if (t < S_SEG) {
        // If the buffer holds int64 little-endian, word 1 is the high word of o[0] == 0.
        // If int32, word 1 is o[1] >= 2 (strictly increasing, o[0] >= 1).
        bool is64 = (o_raw[1] == 0);
        o32[t] = is64 ? o_raw[2 * t] : o_raw[t];
    }
}

// ---------------- Kernel 1: per-segment column sums ----------------
// grid 1024 blocks x 256 threads; block handles 256 rows.
// thread t: rsub = t>>6 (row quarter), cg = t&63 (float4 column group)
__global__ __launch_bounds__(256) void k1_segsum(const float* __restrict__ x,
                                                 const int* __restrict__ o32,
                                                 float* __restrict__ sums) {
    __shared__ int o_s[S_SEG];
    __shared__ float4 partv[256];
    __shared__ int pseg[256];
    int t = threadIdx.x;
    if (t < S_SEG) o_s[t] = o32[t];
    __syncthreads();

    int rsub = t >> 6, cg = t & 63;
    int row0 = blockIdx.x * 256 + rsub * 64;
    const float4* xv = (const float4*)x;

    int cur = 0;
#pragma unroll
    for (int j = 0; j < S_SEG; ++j) cur += (row0 >= o_s[j]);
    int next = o_s[cur];

    float4 acc = make_float4(0.f, 0.f, 0.f, 0.f);
    for (int i = 0; i < 64; ++i) {
        int row = row0 + i;
        if (row >= next) {  // rare: segment boundary inside this thread's rows
            atomicAdd(&sums[cur * C_DIM + cg * 4 + 0], acc.x);
            atomicAdd(&sums[cur * C_DIM + cg * 4 + 1], acc.y);
            atomicAdd(&sums[cur * C_DIM + cg * 4 + 2], acc.z);
            atomicAdd(&sums[cur * C_DIM + cg * 4 + 3], acc.w);
            acc = make_float4(0.f, 0.f, 0.f, 0.f);
            do { cur++; next = o_s[cur]; } while (row >= next);
        }
        float4 v = xv[row * 64 + cg];
        acc.x += v.x; acc.y += v.y; acc.z += v.z; acc.w += v.w;
    }
    partv[t] = acc;
    pseg[t] = cur;
    __syncthreads();

    if (t < 64) {  // merge the 4 row-quarters per column group (segs non-decreasing)
        float4 a = partv[t];
        int s = pseg[t];
        for (int i = 1; i < 4; ++i) {
            int idx = i * 64 + t;
            int s2 = pseg[idx];
            float4 a2 = partv[idx];
            if (s2 == s) {
                a.x += a2.x; a.y += a2.y; a.z += a2.z; a.w += a2.w;
            } else {
                atomicAdd(&sums[s * C_DIM + t * 4 + 0], a.x);
                atomicAdd(&sums[s * C_DIM + t * 4 + 1], a.y);
                atomicAdd(&sums[s * C_DIM + t * 4 + 2], a.z);
                atomicAdd(&sums[s * C_DIM + t * 4 + 3], a.w);
                s = s2; a = a2;
            }
        }
        atomicAdd(&sums[s * C_DIM + t * 4 + 0], a.x);
        atomicAdd(&sums[s * C_DIM + t * 4 + 1], a.y);
        atomicAdd(&sums[s * C_DIM + t * 4 + 2], a.z);
        atomicAdd(&sums[s * C_DIM + t * 4 + 3], a.w);
    }
}

// ---------------- Kernel 2: tiny per-segment math + W1s bf16 fragment-layout conversion
// blocks 0..15: segment s -> mean -> h=relu(mean@W2+b2) -> Cseg[s][c]
// blocks 16..23: W1s[k][c] = bf16(W1[k][c]*scale[c]) stored in MFMA B-fragment order
__global__ __launch_bounds__(256) void k2_small(const float* __restrict__ sums,
                                                const int* __restrict__ o32,
                                                const float* __restrict__ W2,
                                                const float* __restrict__ b2,
                                                const float* __restrict__ W1,
                                                const float* __restrict__ b1,
                                                const float* __restrict__ gamma,
                                                const float* __restrict__ beta,
                                                const float* __restrict__ rmean,
                                                const float* __restrict__ rvar,
                                                float* __restrict__ Cseg,
                                                short* __restrict__ W1s) {
    int t = threadIdx.x;
    int blk = blockIdx.x;
    if (blk < S_SEG) {
        __shared__ float mean_s[C_DIM];
        __shared__ float h_s[C_DIM];
        int s = blk;
        int lo = (s == 0) ? 0 : o32[s - 1];
        float inv = 1.0f / (float)(o32[s] - lo);
        mean_s[t] = sums[s * C_DIM + t] * inv;
        __syncthreads();
        float acc = b2[t];
#pragma unroll 4
        for (int k = 0; k < C_DIM; ++k) acc = fmaf(mean_s[k], W2[k * C_DIM + t], acc);
        h_s[t] = fmaxf(acc, 0.0f);
        __syncthreads();
        float acc2 = 0.f;
#pragma unroll 4
        for (int k = 0; k < C_DIM; ++k) acc2 = fmaf(h_s[k], W1[(C_DIM + k) * C_DIM + t], acc2);
        float sc = gamma[t] * rsqrtf(rvar[t] + 1e-5f);
        Cseg[s * C_DIM + t] = (b1[t] + acc2 - rmean[t]) * sc + beta[t];
    } else {
        // convert 256x256 W1a*scale -> bf16 in B-fragment order:
        // elem (k,c): kb2=k>>5, q=(k>>3)&3, j=k&7, nsub=c>>4, r=c&15
        // off = ((kb2*16+nsub)*64 + q*16 + r)*8 + j
        int base = (blk - S_SEG) * 8192;  // 8 blocks * 8192 = 65536 elements
        for (int i = 0; i < 32; ++i) {
            int idx = base + i * 256 + t;
            int k = idx >> 8, c = idx & 255;
            float sc = gamma[c] * rsqrtf(rvar[c] + 1e-5f);
            float v = W1[k * C_DIM + c] * sc;
            int kb2 = k >> 5, q = (k >> 3) & 3, j = k & 7, nsub = c >> 4, r = c & 15;
            int off = ((kb2 * 16 + nsub) * 64 + q * 16 + r) * 8 + j;
            W1s[off] = f2bf(v);
        }
    }
}

// ---------------- Kernel 3: out = relu(x @ W1s + Cseg[seg(row)]) -------------
// grid 4096 blocks x 256 threads (4 waves). Block: 64 rows x 256 cols.
// Wave w: cols [w*64, w*64+64), all 64 rows. 4x4 tiles of mfma_f32_16x16x32_bf16.
__global__ __launch_bounds__(256) void k3_gemm(const float* __restrict__ x,
                                               const short* __restrict__ W1s,
                                               const float* __restrict__ Cseg,
                                               const int* __restrict__ o32,
                                               float* __restrict__ out) {
    // A tile LDS: fragment-contiguous [mt(4)][kt(2)][slot(64)][8] bf16, slot swizzled
    __shared__ __align__(16) short As[4 * 2 * 64 * 8];  // 8 KB
    __shared__ float Cs[S_SEG * C_DIM];                  // 16 KB
    __shared__ int o_s[S_SEG];

    int t = threadIdx.x;
    int wave = t >> 6, lane = t & 63;
    int q = lane >> 4, r = lane & 15;
    int wc = wave;  // column quarter
    int m0 = blockIdx.x * 64;

    if (t < S_SEG) o_s[t] = o32[t];
    for (int i = t; i < S_SEG * C_DIM; i += 256) Cs[i] = Cseg[i];

    f32x4 acc[4][4];
#pragma unroll
    for (int mt = 0; mt < 4; ++mt)
#pragma unroll
        for (int nt = 0; nt < 4; ++nt)
            acc[mt][nt] = (f32x4){0.f, 0.f, 0.f, 0.f};

    const float4* xv = (const float4*)x;
    int arow = t >> 3;      // 0..31
    int akc = t & 7;        // 0..7 (8-float k-chunk)
    int kt_w = akc >> 2, q_w = akc & 3;

    for (int kb = 0; kb < 4; ++kb) {
        // global loads: rows arow and arow+32, 8 floats each (two float4)
        long g0 = (long)(m0 + arow) * 64 + kb * 16 + akc * 2;
        long g1 = (long)(m0 + 32 + arow) * 64 + kb * 16 + akc * 2;
        float4 c00 = xv[g0], c01 = xv[g0 + 1];
        float4 c10 = xv[g1], c11 = xv[g1 + 1];

        __syncthreads();  // previous iteration done reading As

        {
            int mt0 = arow >> 4, r0 = arow & 15;
            int slot0 = (mt0 * 2 + kt_w) * 64 + q_w * 16 + (r0 ^ q_w);
            bf16x8 w0;
            w0[0] = f2bf(c00.x); w0[1] = f2bf(c00.y); w0[2] = f2bf(c00.z); w0[3] = f2bf(c00.w);
            w0[4] = f2bf(c01.x); w0[5] = f2bf(c01.y); w0[6] = f2bf(c01.z); w0[7] = f2bf(c01.w);
            *(bf16x8*)&As[slot0 * 8] = w0;

            int row1 = 32 + arow;
            int mt1 = row1 >> 4, r1 = row1 & 15;
            int slot1 = (mt1 * 2 + kt_w) * 64 + q_w * 16 + (r1 ^ q_w);
            bf16x8 w1;
            w1[0] = f2bf(c10.x); w1[1] = f2bf(c10.y); w1[2] = f2bf(c10.z); w1[3] = f2bf(c10.w);
            w1[4] = f2bf(c11.x); w1[5] = f2bf(c11.y); w1[6] = f2bf(c11.z); w1[7] = f2bf(c11.w);
            *(bf16x8*)&As[slot1 * 8] = w1;
        }
        __syncthreads();

#pragma unroll
        for (int kt = 0; kt < 2; ++kt) {
            bf16x8 a[4], b[4];
#pragma unroll
            for (int mt = 0; mt < 4; ++mt)
                a[mt] = *(const bf16x8*)&As[((mt * 2 + kt) * 64 + q * 16 + (r ^ q)) * 8];
#pragma unroll
            for (int nt = 0; nt < 4; ++nt) {
                int nsub = wc * 4 + nt;
                b[nt] = *(const bf16x8*)&W1s[(((kb * 2 + kt) * 16 + nsub) * 64 + lane) * 8];
            }
#pragma unroll
            for (int mt = 0; mt < 4; ++mt)
#pragma unroll
                for (int nt = 0; nt < 4; ++nt)
                    acc[mt][nt] = __builtin_amdgcn_mfma_f32_16x16x32_bf16(a[mt], b[nt], acc[mt][nt], 0, 0, 0);
        }
    }

    // epilogue: D[row=q*4+i within 16][col=r within 16]
#pragma unroll
    for (int mt = 0; mt < 4; ++mt) {
#pragma unroll
        for (int i = 0; i < 4; ++i) {
            int row = m0 + mt * 16 + q * 4 + i;
            int s = 0;
#pragma unroll
            for (int j = 0; j < S_SEG; ++j) s += (row >= o_s[j]);
#pragma unroll
            for (int nt = 0; nt < 4; ++nt) {
                int col = wc * 64 + nt * 16 + r;
                float v = acc[mt][nt][i] + Cs[s * C_DIM + col];
                out[(long)row * C_DIM + col] = fmaxf(v, 0.0f);
            }
        }
    }
}

extern "C" void kernel_launch(void* const* d_in, const int* in_sizes, int n_in,
                              void* d_out, int out_size, void* d_ws, size_t ws_size,
                              hipStream_t stream) {
    const float* x     = (const float*)d_in[0];
    const int*   o     = (const int*)d_in[1];
    const float* W2    = (const float*)d_in[2];
    const float* b2    = (const float*)d_in[3];
    const float* W1    = (const float*)d_in[4];
    const float* b1    = (const float*)d_in[5];
    const float* gamma = (const float*)d_in[6];
    const float* beta  = (const float*)d_in[7];
    const float* rmean = (const float*)d_in[8];
    const float* rvar  = (const float*)d_in[9];
    float* out = (float*)d_out;

    // workspace layout
    float* sums = (float*)d_ws;                           // 16 KB
    float* Cseg = (float*)((char*)d_ws + 16384);          // 16 KB
    int*   o32  = (int*)((char*)d_ws + 32768);            // 64 B
    short* W1s  = (short*)((char*)d_ws + 65536);          // 128 KB

    hipMemsetAsync(d_ws, 0, 16384, stream);  // zero sums
    k0_norm_o<<<1, 64, 0, stream>>>(o, o32);
    k1_segsum<<<1024, 256, 0, stream>>>(x, o32, sums);
    k2_small<<<24, 256, 0, stream>>>(sums, o32, W2, b2, W1, b1, gamma, beta, rmean, rvar, Cseg, W1s);
    k3_gemm<<<4096, 256, 0, stream>>>(x, W1s, Cseg, o32, out);
}

// Round 2
// 600.881 us; speedup vs baseline: 1.0120x; 1.0120x over previous
//
#include <hip/hip_runtime.h>

#define C_DIM 256
#define S_SEG 16

typedef __attribute__((ext_vector_type(8))) short bf16x8;
typedef __attribute__((ext_vector_type(4))) float f32x4;

__device__ __forceinline__ short f2bf(float f) {
    unsigned u = __builtin_bit_cast(unsigned, f);
    u += 0x7FFF + ((u >> 16) & 1);   // round-to-nearest-even
    return (short)(u >> 16);
}

// decode o (int64 or int32 layout) -> value i. If int64, word 1 (= high word of
// o[0]) is 0; if int32, word 1 is o[1] >= 2 (strictly increasing, o[0] >= 1).
__device__ __forceinline__ int o_get(const int* __restrict__ o_raw, int i) {
    return (o_raw[1] == 0) ? o_raw[2 * i] : o_raw[i];
}

// ---------------- Kernel 1: per-segment column sums ----------------
// grid 1024 blocks x 256 threads; block handles 256 rows (ascending order,
// warming L3 with x for k3's reverse-order pass).
__global__ __launch_bounds__(256) void k1_segsum(const float* __restrict__ x,
                                                 const int* __restrict__ o_raw,
                                                 float* __restrict__ sums) {
    __shared__ int o_s[S_SEG];
    __shared__ float4 partv[256];
    __shared__ int pseg[256];
    int t = threadIdx.x;
    if (t < S_SEG) o_s[t] = o_get(o_raw, t);
    __syncthreads();

    int rsub = t >> 6, cg = t & 63;
    int row0 = blockIdx.x * 256 + rsub * 64;
    const float4* xv = (const float4*)x;

    int cur = 0;
#pragma unroll
    for (int j = 0; j < S_SEG; ++j) cur += (row0 >= o_s[j]);
    int next = o_s[cur];

    float4 acc = make_float4(0.f, 0.f, 0.f, 0.f);
    for (int i = 0; i < 64; ++i) {
        int row = row0 + i;
        if (row >= next) {  // rare: segment boundary inside this thread's rows
            atomicAdd(&sums[cur * C_DIM + cg * 4 + 0], acc.x);
            atomicAdd(&sums[cur * C_DIM + cg * 4 + 1], acc.y);
            atomicAdd(&sums[cur * C_DIM + cg * 4 + 2], acc.z);
            atomicAdd(&sums[cur * C_DIM + cg * 4 + 3], acc.w);
            acc = make_float4(0.f, 0.f, 0.f, 0.f);
            do { cur++; next = o_s[cur]; } while (row >= next);
        }
        float4 v = xv[row * 64 + cg];
        acc.x += v.x; acc.y += v.y; acc.z += v.z; acc.w += v.w;
    }
    partv[t] = acc;
    pseg[t] = cur;
    __syncthreads();

    if (t < 64) {  // merge the 4 row-quarters per column group (segs non-decreasing)
        float4 a = partv[t];
        int s = pseg[t];
        for (int i = 1; i < 4; ++i) {
            int idx = i * 64 + t;
            int s2 = pseg[idx];
            float4 a2 = partv[idx];
            if (s2 == s) {
                a.x += a2.x; a.y += a2.y; a.z += a2.z; a.w += a2.w;
            } else {
                atomicAdd(&sums[s * C_DIM + t * 4 + 0], a.x);
                atomicAdd(&sums[s * C_DIM + t * 4 + 1], a.y);
                atomicAdd(&sums[s * C_DIM + t * 4 + 2], a.z);
                atomicAdd(&sums[s * C_DIM + t * 4 + 3], a.w);
                s = s2; a = a2;
            }
        }
        atomicAdd(&sums[s * C_DIM + t * 4 + 0], a.x);
        atomicAdd(&sums[s * C_DIM + t * 4 + 1], a.y);
        atomicAdd(&sums[s * C_DIM + t * 4 + 2], a.z);
        atomicAdd(&sums[s * C_DIM + t * 4 + 3], a.w);
    }
}

// ---------------- Kernel 2: tiny per-segment math + W1s bf16 fragment-layout conversion
__global__ __launch_bounds__(256) void k2_small(const float* __restrict__ sums,
                                                const int* __restrict__ o_raw,
                                                const float* __restrict__ W2,
                                                const float* __restrict__ b2,
                                                const float* __restrict__ W1,
                                                const float* __restrict__ b1,
                                                const float* __restrict__ gamma,
                                                const float* __restrict__ beta,
                                                const float* __restrict__ rmean,
                                                const float* __restrict__ rvar,
                                                float* __restrict__ Cseg,
                                                short* __restrict__ W1s) {
    int t = threadIdx.x;
    int blk = blockIdx.x;
    if (blk < S_SEG) {
        __shared__ float mean_s[C_DIM];
        __shared__ float h_s[C_DIM];
        int s = blk;
        int lo = (s == 0) ? 0 : o_get(o_raw, s - 1);
        float inv = 1.0f / (float)(o_get(o_raw, s) - lo);
        mean_s[t] = sums[s * C_DIM + t] * inv;
        __syncthreads();
        float acc = b2[t];
#pragma unroll 4
        for (int k = 0; k < C_DIM; ++k) acc = fmaf(mean_s[k], W2[k * C_DIM + t], acc);
        h_s[t] = fmaxf(acc, 0.0f);
        __syncthreads();
        float acc2 = 0.f;
#pragma unroll 4
        for (int k = 0; k < C_DIM; ++k) acc2 = fmaf(h_s[k], W1[(C_DIM + k) * C_DIM + t], acc2);
        float sc = gamma[t] * rsqrtf(rvar[t] + 1e-5f);
        Cseg[s * C_DIM + t] = (b1[t] + acc2 - rmean[t]) * sc + beta[t];
    } else {
        // W1s[k][c] = bf16(W1[k][c]*scale[c]) in MFMA B-fragment order:
        // elem (k,c): kb2=k>>5, q=(k>>3)&3, j=k&7, nsub=c>>4, r=c&15
        // off = ((kb2*16+nsub)*64 + q*16 + r)*8 + j
        int base = (blk - S_SEG) * 8192;  // 8 blocks * 8192 = 65536 elements
        for (int i = 0; i < 32; ++i) {
            int idx = base + i * 256 + t;
            int k = idx >> 8, c = idx & 255;
            float sc = gamma[c] * rsqrtf(rvar[c] + 1e-5f);
            float v = W1[k * C_DIM + c] * sc;
            int kb2 = k >> 5, q = (k >> 3) & 3, j = k & 7, nsub = c >> 4, r = c & 15;
            int off = ((kb2 * 16 + nsub) * 64 + q * 16 + r) * 8 + j;
            W1s[off] = f2bf(v);
        }
    }
}

// ---------------- Kernel 3: out = relu(x @ W1s + Cseg[seg(row)]) -------------
// grid 4096 blocks x 256 threads (4 waves). Block: 64 rows x 256 cols.
// Double-buffered A staging in LDS, register prefetch of next k-block,
// single barrier per k-iteration. Tiles processed in REVERSE row order so x
// (just streamed ascending by k1) is served from L3; out stores nontemporal
// to avoid evicting x from L3.
__global__ __launch_bounds__(256) void k3_gemm(const float* __restrict__ x,
                                               const short* __restrict__ W1s,
                                               const float* __restrict__ Cseg,
                                               const int* __restrict__ o_raw,
                                               float* __restrict__ out) {
    __shared__ __align__(16) short As[2][4 * 2 * 64 * 8];  // 2 x 8 KB
    __shared__ int o_s[S_SEG];

    int t = threadIdx.x;
    int wave = t >> 6, lane = t & 63;
    int q = lane >> 4, r = lane & 15;
    int wc = wave;  // column quarter
    int m0 = (int)(gridDim.x - 1 - blockIdx.x) * 64;  // reverse tile order

    if (t < S_SEG) o_s[t] = o_get(o_raw, t);

    f32x4 acc[4][4];
#pragma unroll
    for (int mt = 0; mt < 4; ++mt)
#pragma unroll
        for (int nt = 0; nt < 4; ++nt)
            acc[mt][nt] = (f32x4){0.f, 0.f, 0.f, 0.f};

    const float4* xv = (const float4*)x;
    int arow = t >> 3;      // 0..31
    int akc = t & 7;        // 0..7 (8-float k-chunk)
    int kt_w = akc >> 2, q_w = akc & 3;
    int mt0 = arow >> 4, r0 = arow & 15;
    int slot0 = (mt0 * 2 + kt_w) * 64 + q_w * 16 + (r0 ^ q_w);
    int row1 = 32 + arow, mt1 = row1 >> 4, r1 = row1 & 15;
    int slot1 = (mt1 * 2 + kt_w) * 64 + q_w * 16 + (r1 ^ q_w);
    long gbase0 = (long)(m0 + arow) * 64 + akc * 2;
    long gbase1 = (long)(m0 + 32 + arow) * 64 + akc * 2;

    float4 c00, c01, c10, c11;
    // prologue: load kb=0, stage into buffer 0
    c00 = xv[gbase0]; c01 = xv[gbase0 + 1];
    c10 = xv[gbase1]; c11 = xv[gbase1 + 1];
    {
        bf16x8 w0, w1;
        w0[0] = f2bf(c00.x); w0[1] = f2bf(c00.y); w0[2] = f2bf(c00.z); w0[3] = f2bf(c00.w);
        w0[4] = f2bf(c01.x); w0[5] = f2bf(c01.y); w0[6] = f2bf(c01.z); w0[7] = f2bf(c01.w);
        *(bf16x8*)&As[0][slot0 * 8] = w0;
        w1[0] = f2bf(c10.x); w1[1] = f2bf(c10.y); w1[2] = f2bf(c10.z); w1[3] = f2bf(c10.w);
        w1[4] = f2bf(c11.x); w1[5] = f2bf(c11.y); w1[6] = f2bf(c11.z); w1[7] = f2bf(c11.w);
        *(bf16x8*)&As[0][slot1 * 8] = w1;
    }
    __syncthreads();

    for (int kb = 0; kb < 4; ++kb) {
        if (kb < 3) {  // prefetch next k-block while MFMAing this one
            long o = (long)(kb + 1) * 16;
            c00 = xv[gbase0 + o]; c01 = xv[gbase0 + o + 1];
            c10 = xv[gbase1 + o]; c11 = xv[gbase1 + o + 1];
        }
        const short* Ab = As[kb & 1];
#pragma unroll
        for (int kt = 0; kt < 2; ++kt) {
            bf16x8 a[4], b[4];
#pragma unroll
            for (int mt = 0; mt < 4; ++mt)
                a[mt] = *(const bf16x8*)&Ab[((mt * 2 + kt) * 64 + q * 16 + (r ^ q)) * 8];
#pragma unroll
            for (int nt = 0; nt < 4; ++nt)
                b[nt] = *(const bf16x8*)&W1s[(((kb * 2 + kt) * 16 + wc * 4 + nt) * 64 + lane) * 8];
#pragma unroll
            for (int mt = 0; mt < 4; ++mt)
#pragma unroll
                for (int nt = 0; nt < 4; ++nt)
                    acc[mt][nt] = __builtin_amdgcn_mfma_f32_16x16x32_bf16(a[mt], b[nt], acc[mt][nt], 0, 0, 0);
        }
        if (kb < 3) {
            short* Aw = As[(kb + 1) & 1];
            bf16x8 w0, w1;
            w0[0] = f2bf(c00.x); w0[1] = f2bf(c00.y); w0[2] = f2bf(c00.z); w0[3] = f2bf(c00.w);
            w0[4] = f2bf(c01.x); w0[5] = f2bf(c01.y); w0[6] = f2bf(c01.z); w0[7] = f2bf(c01.w);
            *(bf16x8*)&Aw[slot0 * 8] = w0;
            w1[0] = f2bf(c10.x); w1[1] = f2bf(c10.y); w1[2] = f2bf(c10.z); w1[3] = f2bf(c10.w);
            w1[4] = f2bf(c11.x); w1[5] = f2bf(c11.y); w1[6] = f2bf(c11.z); w1[7] = f2bf(c11.w);
            *(bf16x8*)&Aw[slot1 * 8] = w1;
            __syncthreads();
        }
    }

    // epilogue: D[row=q*4+i][col=r]; Cseg row is L1-resident after first touch
#pragma unroll
    for (int mt = 0; mt < 4; ++mt) {
#pragma unroll
        for (int i = 0; i < 4; ++i) {
            int row = m0 + mt * 16 + q * 4 + i;
            int s = 0;
#pragma unroll
            for (int j = 0; j < S_SEG; ++j) s += (row >= o_s[j]);
#pragma unroll
            for (int nt = 0; nt < 4; ++nt) {
                int col = wc * 64 + nt * 16 + r;
                float v = acc[mt][nt][i] + Cseg[s * C_DIM + col];
                __builtin_nontemporal_store(fmaxf(v, 0.0f), &out[(long)row * C_DIM + col]);
            }
        }
    }
}

extern "C" void kernel_launch(void* const* d_in, const int* in_sizes, int n_in,
                              void* d_out, int out_size, void* d_ws, size_t ws_size,
                              hipStream_t stream) {
    const float* x     = (const float*)d_in[0];
    const int*   o     = (const int*)d_in[1];
    const float* W2    = (const float*)d_in[2];
    const float* b2    = (const float*)d_in[3];
    const float* W1    = (const float*)d_in[4];
    const float* b1    = (const float*)d_in[5];
    const float* gamma = (const float*)d_in[6];
    const float* beta  = (const float*)d_in[7];
    const float* rmean = (const float*)d_in[8];
    const float* rvar  = (const float*)d_in[9];
    float* out = (float*)d_out;

    // workspace layout
    float* sums = (float*)d_ws;                           // 16 KB
    float* Cseg = (float*)((char*)d_ws + 16384);          // 16 KB
    short* W1s  = (short*)((char*)d_ws + 65536);          // 128 KB

    hipMemsetAsync(d_ws, 0, 16384, stream);  // zero sums
    k1_segsum<<<1024, 256, 0, stream>>>(x, o, sums);
    k2_small<<<24, 256, 0, stream>>>(sums, o, W2, b2, W1, b1, gamma, beta, rmean, rvar, Cseg, W1s);
    k3_gemm<<<4096, 256, 0, stream>>>(x, W1s, Cseg, o, out);
}